// Round 3
// baseline (561.874 us; speedup 1.0000x reference)
//
#include <hip/hip_runtime.h>

// ---------------------------------------------------------------------------
// WriteMemory: B=512, D_MODEL=2048, H=8, D_MEM=128, M=512
// out = [next_memories (512*512*128) | next_mass (512*512*128)] fp32
// ---------------------------------------------------------------------------

typedef _Float16 half8  __attribute__((ext_vector_type(8)));
typedef _Float16 half4v __attribute__((ext_vector_type(4)));
typedef float    f32x4  __attribute__((ext_vector_type(4)));

#define NB      512
#define DMODEL  2048
#define NH      8
#define DMEM    128
#define NM      512
#define NMTOT   33554432     // 512*512*128

__device__ __forceinline__ f32x4 ntload4(const float* p) {
    return __builtin_nontemporal_load((const f32x4*)p);
}
__device__ __forceinline__ void ntstore4(float* p, f32x4 v) {
    __builtin_nontemporal_store(v, (f32x4*)p);
}

// ---------------------------------------------------------------------------
// K0a: fused prep: key/values fp32->fp16, aq=elu(addr)+1, sigI=sigmoid(ilog)
// blocks 0..1023: key, 1024..2047: values, 2048..2303: aq/sigI
// ---------------------------------------------------------------------------
__global__ void prep_all(const float* __restrict__ key, const float* __restrict__ values,
                         const float* __restrict__ addresses, const float* __restrict__ ilog,
                         _Float16* __restrict__ key16, _Float16* __restrict__ val16,
                         float* __restrict__ aqF, _Float16* __restrict__ aqH,
                         float* __restrict__ sigI) {
    const int bid = blockIdx.x;
    if (bid < 2048) {
        const float* src = (bid < 1024) ? key : values;
        _Float16* dst = (bid < 1024) ? key16 : val16;
        int i = (bid & 1023) * 256 + threadIdx.x;
        float4 v = ((const float4*)src)[i];
        half4v o;
        o[0] = (_Float16)v.x; o[1] = (_Float16)v.y;
        o[2] = (_Float16)v.z; o[3] = (_Float16)v.w;
        ((half4v*)dst)[i] = o;
    } else {
        int i = (bid - 2048) * 256 + threadIdx.x;
        float a = addresses[i];
        float v = a > 0.f ? a + 1.f : __expf(a);
        aqF[i] = v;
        aqH[i] = (_Float16)v;
        sigI[i] = 1.0f / (1.0f + __expf(-ilog[i]));
    }
}

// ---------------------------------------------------------------------------
// K0b: W [K=2048][N] fp32 -> Wt [N][2048] fp16
// ---------------------------------------------------------------------------
__global__ void transp_cvt(const float* __restrict__ W, _Float16* __restrict__ Wt, int N) {
    __shared__ float tile[32][33];
    const int k0 = blockIdx.x * 32, n0 = blockIdx.y * 32;
    const int c = threadIdx.x & 31, r0 = threadIdx.x >> 5;
#pragma unroll
    for (int i = 0; i < 4; i++) {
        int r = r0 + i * 8;
        tile[r][c] = W[(size_t)(k0 + r) * N + n0 + c];
    }
    __syncthreads();
#pragma unroll
    for (int i = 0; i < 4; i++) {
        int r = r0 + i * 8;
        Wt[(size_t)(n0 + r) * 2048 + k0 + c] = (_Float16)tile[c][r];
    }
}

// ---------------------------------------------------------------------------
// K1: fused GEMM C[512][3072] over K=2048, fp16 MFMA 16x16x32.
// ---------------------------------------------------------------------------
__global__ __launch_bounds__(256) void gemm_kv(
        const _Float16* __restrict__ key16,
        const _Float16* __restrict__ val16,
        const _Float16* __restrict__ WkT,
        const _Float16* __restrict__ WvT,
        const float* __restrict__ b_key,
        const float* __restrict__ b_val,
        float* __restrict__ akF,
        _Float16* __restrict__ vH) {
    __shared__ _Float16 As[2][64][72];
    __shared__ _Float16 Bs[2][64][72];

    const int t = threadIdx.x;
    const int m0 = blockIdx.x * 64;
    const int n0 = blockIdx.y * 64;
    const bool isK = (n0 < 1024);
    const _Float16* aSrc = isK ? key16 : val16;
    const _Float16* bSrc = isK ? (WkT + (size_t)n0 * 2048)
                               : (WvT + (size_t)(n0 - 1024) * 2048);

    const int w = t >> 6, lane = t & 63;
    const int col = lane & 15, q = lane >> 4;
    const int wm = (w & 1) * 32, wn = (w >> 1) * 32;

    const int row0 = t >> 3, ch = t & 7;
    const int row1 = (t + 256) >> 3;

    f32x4 acc[2][2];
#pragma unroll
    for (int i = 0; i < 2; i++)
#pragma unroll
        for (int j = 0; j < 2; j++) acc[i][j] = (f32x4){0.f, 0.f, 0.f, 0.f};

    uint4 ra0 = *(const uint4*)(aSrc + (size_t)(m0 + row0) * 2048 + ch * 8);
    uint4 ra1 = *(const uint4*)(aSrc + (size_t)(m0 + row1) * 2048 + ch * 8);
    uint4 rb0 = *(const uint4*)(bSrc + (size_t)row0 * 2048 + ch * 8);
    uint4 rb1 = *(const uint4*)(bSrc + (size_t)row1 * 2048 + ch * 8);

    int buf = 0;
    for (int k0 = 0; k0 < 2048; k0 += 64) {
        *(uint4*)&As[buf][row0][ch * 8] = ra0;
        *(uint4*)&As[buf][row1][ch * 8] = ra1;
        *(uint4*)&Bs[buf][row0][ch * 8] = rb0;
        *(uint4*)&Bs[buf][row1][ch * 8] = rb1;
        if (k0 + 64 < 2048) {
            const int kn = k0 + 64;
            ra0 = *(const uint4*)(aSrc + (size_t)(m0 + row0) * 2048 + kn + ch * 8);
            ra1 = *(const uint4*)(aSrc + (size_t)(m0 + row1) * 2048 + kn + ch * 8);
            rb0 = *(const uint4*)(bSrc + (size_t)row0 * 2048 + kn + ch * 8);
            rb1 = *(const uint4*)(bSrc + (size_t)row1 * 2048 + kn + ch * 8);
        }
        __syncthreads();
#pragma unroll
        for (int ks = 0; ks < 2; ks++) {
            half8 a0 = *(const half8*)&As[buf][wm + col][ks * 32 + q * 8];
            half8 a1 = *(const half8*)&As[buf][wm + 16 + col][ks * 32 + q * 8];
            half8 b0 = *(const half8*)&Bs[buf][wn + col][ks * 32 + q * 8];
            half8 b1 = *(const half8*)&Bs[buf][wn + 16 + col][ks * 32 + q * 8];
            acc[0][0] = __builtin_amdgcn_mfma_f32_16x16x32_f16(a0, b0, acc[0][0], 0, 0, 0);
            acc[0][1] = __builtin_amdgcn_mfma_f32_16x16x32_f16(a0, b1, acc[0][1], 0, 0, 0);
            acc[1][0] = __builtin_amdgcn_mfma_f32_16x16x32_f16(a1, b0, acc[1][0], 0, 0, 0);
            acc[1][1] = __builtin_amdgcn_mfma_f32_16x16x32_f16(a1, b1, acc[1][1], 0, 0, 0);
        }
        buf ^= 1;
    }
#pragma unroll
    for (int mt = 0; mt < 2; mt++) {
#pragma unroll
        for (int nt = 0; nt < 2; nt++) {
            int n = n0 + wn + nt * 16 + col;
#pragma unroll
            for (int r = 0; r < 4; r++) {
                int m = m0 + wm + mt * 16 + q * 4 + r;
                float x = acc[mt][nt][r];
                if (isK) {
                    x += b_key[n];
                    akF[(size_t)m * 1024 + n] = (x > 0.f) ? (x + 1.f) : __expf(x);
                } else {
                    int nn = n - 1024;
                    x += b_val[nn];
                    vH[(size_t)m * 2048 + nn] = (_Float16)x;
                }
            }
        }
    }
}

// ---------------------------------------------------------------------------
// K3: per-(batch, e-half) fused kernel. 512 threads = 8 waves, 2 blocks/CU.
// v3: prefetch depth 2 for the HBM streams (memories/write_mass triple-
// buffered M0/M1/M2), depth 1 for L2-hot sigI (S0/S1). Per-CU in-flight
// load bytes ~2x (49KB -> 98KB per block) so the vmem queue stays full
// across the MFMA/restage phases (v2 measured 65% of the per-CU BW floor
// with a queue-empty gap matching depth-1 arithmetic).
// LDS: 34816 + 17408*2 + 4096 + 2048 + 512 + 2048 = 78336 B -> 2 blocks/CU.
// ---------------------------------------------------------------------------
struct MWBuf { f32x4 pm[2]; f32x4 pw[2]; };
struct PSBuf { f32x4 ps[2]; };

__global__ __launch_bounds__(512, 4) void fused_mem(
    const float* __restrict__ akF,        // [512][1024]
    const _Float16* __restrict__ vH,      // [512][2048]
    const _Float16* __restrict__ aqH,     // [512][128]
    const float* __restrict__ aqF,        // [512][128]
    const float* __restrict__ sigI,       // [512][128]
    const float* __restrict__ memories,   // [512][512][128]
    const float* __restrict__ write_mass, // [512][512][128]
    const unsigned char* __restrict__ bmask,
    float* __restrict__ out) {
    __shared__ _Float16 matT[128][DMEM + 8];   // 34816 B (rows: 64 upd + 64 logit)
    __shared__ float    uT[64][68];            // 17408 B
    __shared__ float    gT[64][68];            // 17408 B
    __shared__ float    sA[NH][DMEM];          // 4096 B
    __shared__ _Float16 sV[NH][128];           // 2048 B (local e slice)
    __shared__ float    sNrm[DMEM];            // 512 B
    __shared__ float    sDen[NM];              // 2048 B

    const int b  = blockIdx.x;
    const int eh = blockIdx.y;                 // e-half: 0 or 1
    const int t = threadIdx.x;
    const int w = t >> 6, lane = t & 63;
    const int col = lane & 15, q = lane >> 4;
    const int wq = w >> 1, slice = w & 1;      // m-quarter, 32-e slice
    const size_t obase = (size_t)b * (NM * DMEM);
    const int ebase = eh * 64;

    // step s: it = s>>2, mt = s&3.
    // IO row-local x in 0..63 -> m = (x>>4)*64 + it*256 + mt*16 + (x&15)
    auto issue_mw = [&](MWBuf& pb, int s) {
        const int it = s >> 2, mt = s & 3;
        const int e4 = ebase + (lane & 15) * 4;
#pragma unroll
        for (int p = 0; p < 2; p++) {
            const int x = w * 8 + p * 4 + (lane >> 4);
            const int m = (x >> 4) * 64 + it * 256 + mt * 16 + (x & 15);
            const size_t gi = (size_t)m * 128 + e4;
            pb.pm[p] = ntload4(memories + obase + gi);
            pb.pw[p] = ntload4(write_mass + obase + gi);
        }
    };
    auto issue_ps = [&](PSBuf& pb, int s) {
        const int it = s >> 2, mt = s & 3;
        const int e4 = ebase + (lane & 15) * 4;
#pragma unroll
        for (int p = 0; p < 2; p++) {
            const int x = w * 8 + p * 4 + (lane >> 4);
            const int m = (x >> 4) * 64 + it * 256 + mt * 16 + (x & 15);
            pb.ps[p] = *(const f32x4*)(sigI + (size_t)m * 128 + e4);
        }
    };

    MWBuf M0, M1, M2;
    PSBuf S0, S1;

    // prologue prefetch: steps 0,1 of mem/wms + step 0 of sigI in flight
    issue_mw(M0, 0);
    issue_ps(S0, 0);
    issue_mw(M1, 1);

    // ---- stage ak[b] (full) and v[b] (local e slice) ----
    if (t < 256) {
        ((float4*)&sA[0][0])[t] = ((const float4*)(akF + (size_t)b * 1024))[t];
    }
    if (t < 128) {
        const int h = t >> 4, grp = t & 15;
        const int eg = (grp < 8) ? (ebase + grp * 8) : (128 + ebase + (grp - 8) * 8);
        *(half8*)&sV[h][grp * 8] = *(const half8*)(vH + (size_t)b * 2048 + h * 256 + eg);
    }
    __syncthreads();

    // ---- normalizer ----
    if (t < 128) {
        float s = 0.f;
#pragma unroll
        for (int h = 0; h < NH; h++) s += sA[h][t];
        sNrm[t] = s;
    }

    // ---- matT build: 512 threads, each 4 d x 8 local-e ----
    {
        const int d0 = (t & 31) * 4;
        const int e0 = (t >> 5) * 8;     // local rows 0..127
        float c[8][4];
#pragma unroll
        for (int e = 0; e < 8; e++)
#pragma unroll
            for (int d = 0; d < 4; d++) c[e][d] = 0.f;
#pragma unroll
        for (int h = 0; h < NH; h++) {
            float4 av = *(const float4*)&sA[h][d0];
            half8 vv = *(const half8*)&sV[h][e0];
#pragma unroll
            for (int e = 0; e < 8; e++) {
                float vf = (float)vv[e];
                c[e][0] += av.x * vf; c[e][1] += av.y * vf;
                c[e][2] += av.z * vf; c[e][3] += av.w * vf;
            }
        }
#pragma unroll
        for (int e = 0; e < 8; e++) {
            half4v o;
            o[0] = (_Float16)c[e][0]; o[1] = (_Float16)c[e][1];
            o[2] = (_Float16)c[e][2]; o[3] = (_Float16)c[e][3];
            *(half4v*)&matT[e0 + e][d0] = o;
        }
    }
    __syncthreads();

    // ---- denominators: 32 passes, 16 m per pass (8 waves x 2) ----
    {
        const int l32 = lane & 31;
        const int hh = lane >> 5;
        const float4 nv = *(const float4*)&sNrm[l32 * 4];
#pragma unroll 4
        for (int pass = 0; pass < 32; pass++) {
            int m = pass * 16 + w * 2 + hh;
            float4 qv = *(const float4*)(aqF + (size_t)m * 128 + l32 * 4);
            float s = qv.x * nv.x + qv.y * nv.y + qv.z * nv.z + qv.w * nv.w;
            s += __shfl_xor(s, 1);  s += __shfl_xor(s, 2);  s += __shfl_xor(s, 4);
            s += __shfl_xor(s, 8);  s += __shfl_xor(s, 16);
            if (l32 == 0) sDen[m] = 1.0f / (s + 1e-5f);
        }
    }
    __syncthreads();

    // ---- phase C ----
    const float wfscale = (bmask[b] != 0) ? 0.0f : 0.7f;

    auto do_step = [&](int s, MWBuf& cm, PSBuf& cs, MWBuf& nm, PSBuf& ns) {
        // 1. prefetch: mem/wms two steps ahead, sigI one step ahead
        if (s + 2 < 8) issue_mw(nm, s + 2);
        if (s + 1 < 8) issue_ps(ns, s + 1);

        // 2. MFMA: acc[nt] nt0/1 = update 16-e frags, nt2/3 = logit frags
        const int it = s >> 2, mt = s & 3;
        const int mrowBase = (wq + it * 4) * 64 + mt * 16;
        f32x4 acc[4];
#pragma unroll
        for (int nt = 0; nt < 4; nt++) acc[nt] = (f32x4){0.f, 0.f, 0.f, 0.f};
#pragma unroll
        for (int ks = 0; ks < 4; ks++) {
            const half8 af = *(const half8*)(aqH + (size_t)(mrowBase + col) * 128
                                             + ks * 32 + q * 8);
#pragma unroll
            for (int nt = 0; nt < 4; nt++) {
                const half8 bf = *(const half8*)&matT[(nt >> 1) * 64 + slice * 32
                                                      + (nt & 1) * 16 + col]
                                                     [ks * 32 + q * 8];
                acc[nt] = __builtin_amdgcn_mfma_f32_16x16x32_f16(af, bf, acc[nt], 0, 0, 0);
            }
        }

        // 3. barrier 1 (WAR on uT/gT): lgkmcnt-only wait, vmcnt stays live
        asm volatile("s_waitcnt lgkmcnt(0)" ::: "memory");
        __builtin_amdgcn_s_barrier();
        __builtin_amdgcn_sched_barrier(0);

        // 4. restage: D layout col=lane&15 (=e-local), row=q*4+r (=m-local)
        const int r0 = wq * 16 + q * 4;
#pragma unroll
        for (int r = 0; r < 4; r++) {
            uT[r0 + r][slice * 32 + col]      = acc[0][r];
            uT[r0 + r][slice * 32 + 16 + col] = acc[1][r];
            gT[r0 + r][slice * 32 + col]      = acc[2][r];
            gT[r0 + r][slice * 32 + 16 + col] = acc[3][r];
        }

        // 5. barrier 2: all restage writes visible
        asm volatile("s_waitcnt lgkmcnt(0)" ::: "memory");
        __builtin_amdgcn_s_barrier();
        __builtin_amdgcn_sched_barrier(0);

        // 6. coalesced IO: row chunk = 256B contiguous (2 full lines)
        const int e4l = (lane & 15) * 4;
#pragma unroll
        for (int p = 0; p < 2; p++) {
            const int x = w * 8 + p * 4 + (lane >> 4);
            const int m = (x >> 4) * 64 + it * 256 + mt * 16 + (x & 15);
            const f32x4 u = *(const f32x4*)&uT[x][e4l];
            const f32x4 g = *(const f32x4*)&gT[x][e4l];
            const float rc = sDen[m];
            const size_t gi = obase + (size_t)m * 128 + ebase + e4l;
            f32x4 o1, o2;
#pragma unroll
            for (int j = 0; j < 4; j++) {
                const float upd = u[j] * rc;
                const float wl  = g[j] * rc;
                const float wpb = 1.0f / (1.0f + __expf(-wl));
                const float wf  = wfscale * wpb * cs.ps[p][j];
                o1[j] = cm.pm[p][j] + wf * (upd - cm.pm[p][j]);
                o2[j] = cm.pw[p][j] + wf;
            }
            ntstore4(out + gi, o1);
            ntstore4(out + NMTOT + gi, o2);
        }
    };

    // explicit rotation: consume M(s%3), S(s%2); issue M(s+2), S(s+1)
    do_step(0, M0, S0, M2, S1);
    do_step(1, M1, S1, M0, S0);
    do_step(2, M2, S0, M1, S1);
    do_step(3, M0, S1, M2, S0);
    do_step(4, M1, S0, M0, S1);
    do_step(5, M2, S1, M1, S0);
    do_step(6, M0, S0, M2, S1);
    do_step(7, M1, S1, M0, S0);
}

// ---------------------------------------------------------------------------
extern "C" void kernel_launch(void* const* d_in, const int* in_sizes, int n_in,
                              void* d_out, int out_size, void* d_ws, size_t ws_size,
                              hipStream_t stream) {
    const float* key        = (const float*)d_in[0];
    const float* values     = (const float*)d_in[1];
    const float* memories   = (const float*)d_in[2];
    const float* write_mass = (const float*)d_in[3];
    const unsigned char* bm = (const unsigned char*)d_in[4];
    const float* W_key      = (const float*)d_in[5];
    const float* b_key      = (const float*)d_in[6];
    const float* W_val      = (const float*)d_in[7];
    const float* b_val      = (const float*)d_in[8];
    const float* addresses  = (const float*)d_in[9];
    const float* ilog       = (const float*)d_in[10];
    float* out = (float*)d_out;

    char* ws = (char*)d_ws;
    _Float16* key16 = (_Float16*)ws;  ws += (size_t)512 * 2048 * 2;
    _Float16* val16 = (_Float16*)ws;  ws += (size_t)512 * 2048 * 2;
    _Float16* WkT   = (_Float16*)ws;  ws += (size_t)1024 * 2048 * 2;
    _Float16* WvT   = (_Float16*)ws;  ws += (size_t)2048 * 2048 * 2;
    float*    akF   = (float*)ws;     ws += (size_t)512 * 1024 * 4;
    _Float16* vH    = (_Float16*)ws;  ws += (size_t)512 * 2048 * 2;
    float*    aqF   = (float*)ws;     ws += (size_t)512 * 128 * 4;
    _Float16* aqH   = (_Float16*)ws;  ws += (size_t)512 * 128 * 2;
    float*    sigI  = (float*)ws;     ws += (size_t)512 * 128 * 4;

    prep_all<<<2304, 256, 0, stream>>>(key, values, addresses, ilog,
                                       key16, val16, aqF, aqH, sigI);
    transp_cvt<<<dim3(64, 32), 256, 0, stream>>>(W_key, WkT, 1024);
    transp_cvt<<<dim3(64, 64), 256, 0, stream>>>(W_val, WvT, 2048);
    gemm_kv<<<dim3(8, 48), 256, 0, stream>>>(key16, val16, WkT, WvT, b_key, b_val, akF, vH);
    fused_mem<<<dim3(512, 2), 512, 0, stream>>>(akF, vH, aqH, aqF, sigI, memories, write_mass, bm, out);
}

// Round 4
// 537.107 us; speedup vs baseline: 1.0461x; 1.0461x over previous
//
#include <hip/hip_runtime.h>

// ---------------------------------------------------------------------------
// WriteMemory: B=512, D_MODEL=2048, H=8, D_MEM=128, M=512
// out = [next_memories (512*512*128) | next_mass (512*512*128)] fp32
// ---------------------------------------------------------------------------

typedef _Float16 half8  __attribute__((ext_vector_type(8)));
typedef _Float16 half4v __attribute__((ext_vector_type(4)));
typedef float    f32x4  __attribute__((ext_vector_type(4)));

#define NB      512
#define DMODEL  2048
#define NH      8
#define DMEM    128
#define NM      512
#define NMTOT   33554432     // 512*512*128

__device__ __forceinline__ f32x4 ntload4(const float* p) {
    return __builtin_nontemporal_load((const f32x4*)p);
}
__device__ __forceinline__ void ntstore4(float* p, f32x4 v) {
    __builtin_nontemporal_store(v, (f32x4*)p);
}

// ---------------------------------------------------------------------------
// K0a: fused prep: key/values fp32->fp16, aq=elu(addr)+1, sigI=sigmoid(ilog)
// blocks 0..1023: key, 1024..2047: values, 2048..2303: aq/sigI
// ---------------------------------------------------------------------------
__global__ void prep_all(const float* __restrict__ key, const float* __restrict__ values,
                         const float* __restrict__ addresses, const float* __restrict__ ilog,
                         _Float16* __restrict__ key16, _Float16* __restrict__ val16,
                         float* __restrict__ aqF, _Float16* __restrict__ aqH,
                         float* __restrict__ sigI) {
    const int bid = blockIdx.x;
    if (bid < 2048) {
        const float* src = (bid < 1024) ? key : values;
        _Float16* dst = (bid < 1024) ? key16 : val16;
        int i = (bid & 1023) * 256 + threadIdx.x;
        float4 v = ((const float4*)src)[i];
        half4v o;
        o[0] = (_Float16)v.x; o[1] = (_Float16)v.y;
        o[2] = (_Float16)v.z; o[3] = (_Float16)v.w;
        ((half4v*)dst)[i] = o;
    } else {
        int i = (bid - 2048) * 256 + threadIdx.x;
        float a = addresses[i];
        float v = a > 0.f ? a + 1.f : __expf(a);
        aqF[i] = v;
        aqH[i] = (_Float16)v;
        sigI[i] = 1.0f / (1.0f + __expf(-ilog[i]));
    }
}

// ---------------------------------------------------------------------------
// K0b: W [K=2048][N] fp32 -> Wt [N][2048] fp16
// ---------------------------------------------------------------------------
__global__ void transp_cvt(const float* __restrict__ W, _Float16* __restrict__ Wt, int N) {
    __shared__ float tile[32][33];
    const int k0 = blockIdx.x * 32, n0 = blockIdx.y * 32;
    const int c = threadIdx.x & 31, r0 = threadIdx.x >> 5;
#pragma unroll
    for (int i = 0; i < 4; i++) {
        int r = r0 + i * 8;
        tile[r][c] = W[(size_t)(k0 + r) * N + n0 + c];
    }
    __syncthreads();
#pragma unroll
    for (int i = 0; i < 4; i++) {
        int r = r0 + i * 8;
        Wt[(size_t)(n0 + r) * 2048 + k0 + c] = (_Float16)tile[c][r];
    }
}

// ---------------------------------------------------------------------------
// K1: fused GEMM C[512][3072] over K=2048, fp16 MFMA 16x16x32.
// ---------------------------------------------------------------------------
__global__ __launch_bounds__(256) void gemm_kv(
        const _Float16* __restrict__ key16,
        const _Float16* __restrict__ val16,
        const _Float16* __restrict__ WkT,
        const _Float16* __restrict__ WvT,
        const float* __restrict__ b_key,
        const float* __restrict__ b_val,
        float* __restrict__ akF,
        _Float16* __restrict__ vH) {
    __shared__ _Float16 As[2][64][72];
    __shared__ _Float16 Bs[2][64][72];

    const int t = threadIdx.x;
    const int m0 = blockIdx.x * 64;
    const int n0 = blockIdx.y * 64;
    const bool isK = (n0 < 1024);
    const _Float16* aSrc = isK ? key16 : val16;
    const _Float16* bSrc = isK ? (WkT + (size_t)n0 * 2048)
                               : (WvT + (size_t)(n0 - 1024) * 2048);

    const int w = t >> 6, lane = t & 63;
    const int col = lane & 15, q = lane >> 4;
    const int wm = (w & 1) * 32, wn = (w >> 1) * 32;

    const int row0 = t >> 3, ch = t & 7;
    const int row1 = (t + 256) >> 3;

    f32x4 acc[2][2];
#pragma unroll
    for (int i = 0; i < 2; i++)
#pragma unroll
        for (int j = 0; j < 2; j++) acc[i][j] = (f32x4){0.f, 0.f, 0.f, 0.f};

    uint4 ra0 = *(const uint4*)(aSrc + (size_t)(m0 + row0) * 2048 + ch * 8);
    uint4 ra1 = *(const uint4*)(aSrc + (size_t)(m0 + row1) * 2048 + ch * 8);
    uint4 rb0 = *(const uint4*)(bSrc + (size_t)row0 * 2048 + ch * 8);
    uint4 rb1 = *(const uint4*)(bSrc + (size_t)row1 * 2048 + ch * 8);

    int buf = 0;
    for (int k0 = 0; k0 < 2048; k0 += 64) {
        *(uint4*)&As[buf][row0][ch * 8] = ra0;
        *(uint4*)&As[buf][row1][ch * 8] = ra1;
        *(uint4*)&Bs[buf][row0][ch * 8] = rb0;
        *(uint4*)&Bs[buf][row1][ch * 8] = rb1;
        if (k0 + 64 < 2048) {
            const int kn = k0 + 64;
            ra0 = *(const uint4*)(aSrc + (size_t)(m0 + row0) * 2048 + kn + ch * 8);
            ra1 = *(const uint4*)(aSrc + (size_t)(m0 + row1) * 2048 + kn + ch * 8);
            rb0 = *(const uint4*)(bSrc + (size_t)row0 * 2048 + kn + ch * 8);
            rb1 = *(const uint4*)(bSrc + (size_t)row1 * 2048 + kn + ch * 8);
        }
        __syncthreads();
#pragma unroll
        for (int ks = 0; ks < 2; ks++) {
            half8 a0 = *(const half8*)&As[buf][wm + col][ks * 32 + q * 8];
            half8 a1 = *(const half8*)&As[buf][wm + 16 + col][ks * 32 + q * 8];
            half8 b0 = *(const half8*)&Bs[buf][wn + col][ks * 32 + q * 8];
            half8 b1 = *(const half8*)&Bs[buf][wn + 16 + col][ks * 32 + q * 8];
            acc[0][0] = __builtin_amdgcn_mfma_f32_16x16x32_f16(a0, b0, acc[0][0], 0, 0, 0);
            acc[0][1] = __builtin_amdgcn_mfma_f32_16x16x32_f16(a0, b1, acc[0][1], 0, 0, 0);
            acc[1][0] = __builtin_amdgcn_mfma_f32_16x16x32_f16(a1, b0, acc[1][0], 0, 0, 0);
            acc[1][1] = __builtin_amdgcn_mfma_f32_16x16x32_f16(a1, b1, acc[1][1], 0, 0, 0);
        }
        buf ^= 1;
    }
#pragma unroll
    for (int mt = 0; mt < 2; mt++) {
#pragma unroll
        for (int nt = 0; nt < 2; nt++) {
            int n = n0 + wn + nt * 16 + col;
#pragma unroll
            for (int r = 0; r < 4; r++) {
                int m = m0 + wm + mt * 16 + q * 4 + r;
                float x = acc[mt][nt][r];
                if (isK) {
                    x += b_key[n];
                    akF[(size_t)m * 1024 + n] = (x > 0.f) ? (x + 1.f) : __expf(x);
                } else {
                    int nn = n - 1024;
                    x += b_val[nn];
                    vH[(size_t)m * 2048 + nn] = (_Float16)x;
                }
            }
        }
    }
}

// ---------------------------------------------------------------------------
// K3: per-(batch, e-half) fused kernel. 512 threads = 8 waves, 2 blocks/CU.
// v4: WAVE-AUTONOMOUS phase C. After the (barriered) prologue, each wave
// owns m-rows [w*64, w*64+64) and runs 4 independent steps of
// { issue mem/wms loads -> MFMA 16m x (64e upd + 64e logit) ->
//   in-wave transpose via private wsT[16][68] -> fused IO }.
// NO block barriers in the loop: waves drift and self-interleave their
// load / MFMA / LDS / store phases, keeping the CU's memory pipe
// continuously fed (v0-v2 were barrier-locked: bursty issue, ~55% of the
// per-CU streaming floor; v3's depth-2 register prefetch spilled at the
// allocator's 64-VGPR heuristic -> scratch traffic, reverted).
// Coalescing unchanged: each global instr covers 4 x 256B segments.
// LDS: 34816 + 34816 + 4096 + 2048 + 512 + 2048 = 78336 B -> 2 blocks/CU.
// ---------------------------------------------------------------------------
__global__ __launch_bounds__(512, 4) void fused_mem(
    const float* __restrict__ akF,        // [512][1024]
    const _Float16* __restrict__ vH,      // [512][2048]
    const _Float16* __restrict__ aqH,     // [512][128]
    const float* __restrict__ aqF,        // [512][128]
    const float* __restrict__ sigI,       // [512][128]
    const float* __restrict__ memories,   // [512][512][128]
    const float* __restrict__ write_mass, // [512][512][128]
    const unsigned char* __restrict__ bmask,
    float* __restrict__ out) {
    __shared__ _Float16 matT[128][DMEM + 8];   // 34816 B (rows: 64 upd + 64 logit)
    __shared__ float    wsT[8][16][68];        // 34816 B per-wave transpose scratch
    __shared__ float    sA[NH][DMEM];          // 4096 B
    __shared__ _Float16 sV[NH][128];           // 2048 B (local e slice)
    __shared__ float    sNrm[DMEM];            // 512 B
    __shared__ float    sDen[NM];              // 2048 B

    const int b  = blockIdx.x;
    const int eh = blockIdx.y;                 // e-half: 0 or 1
    const int t = threadIdx.x;
    const int w = t >> 6, lane = t & 63;
    const int col = lane & 15, q = lane >> 4;
    const size_t obase = (size_t)b * (NM * DMEM);
    const int ebase = eh * 64;

    // IO lane map: lane -> (row group rr = lane>>4, 16B col chunk c4)
    const int rr = lane >> 4;
    const int c4 = (lane & 15) * 4;

    // ---- stage ak[b] (full) and v[b] (local e slice) ----
    if (t < 256) {
        ((float4*)&sA[0][0])[t] = ((const float4*)(akF + (size_t)b * 1024))[t];
    }
    if (t < 128) {
        const int h = t >> 4, grp = t & 15;
        const int eg = (grp < 8) ? (ebase + grp * 8) : (128 + ebase + (grp - 8) * 8);
        *(half8*)&sV[h][grp * 8] = *(const half8*)(vH + (size_t)b * 2048 + h * 256 + eg);
    }
    __syncthreads();

    // ---- normalizer ----
    if (t < 128) {
        float s = 0.f;
#pragma unroll
        for (int h = 0; h < NH; h++) s += sA[h][t];
        sNrm[t] = s;
    }

    // ---- matT build: 512 threads, each 4 d x 8 local-e ----
    {
        const int d0 = (t & 31) * 4;
        const int e0 = (t >> 5) * 8;     // local rows 0..127
        float c[8][4];
#pragma unroll
        for (int e = 0; e < 8; e++)
#pragma unroll
            for (int d = 0; d < 4; d++) c[e][d] = 0.f;
#pragma unroll
        for (int h = 0; h < NH; h++) {
            float4 av = *(const float4*)&sA[h][d0];
            half8 vv = *(const half8*)&sV[h][e0];
#pragma unroll
            for (int e = 0; e < 8; e++) {
                float vf = (float)vv[e];
                c[e][0] += av.x * vf; c[e][1] += av.y * vf;
                c[e][2] += av.z * vf; c[e][3] += av.w * vf;
            }
        }
#pragma unroll
        for (int e = 0; e < 8; e++) {
            half4v o;
            o[0] = (_Float16)c[e][0]; o[1] = (_Float16)c[e][1];
            o[2] = (_Float16)c[e][2]; o[3] = (_Float16)c[e][3];
            *(half4v*)&matT[e0 + e][d0] = o;
        }
    }
    __syncthreads();

    // ---- denominators: 32 passes, 16 m per pass (8 waves x 2) ----
    {
        const int l32 = lane & 31;
        const int hh = lane >> 5;
        const float4 nv = *(const float4*)&sNrm[l32 * 4];
#pragma unroll 4
        for (int pass = 0; pass < 32; pass++) {
            int m = pass * 16 + w * 2 + hh;
            float4 qv = *(const float4*)(aqF + (size_t)m * 128 + l32 * 4);
            float s = qv.x * nv.x + qv.y * nv.y + qv.z * nv.z + qv.w * nv.w;
            s += __shfl_xor(s, 1);  s += __shfl_xor(s, 2);  s += __shfl_xor(s, 4);
            s += __shfl_xor(s, 8);  s += __shfl_xor(s, 16);
            if (l32 == 0) sDen[m] = 1.0f / (s + 1e-5f);
        }
    }
    __syncthreads();

    // ---- phase C: wave-autonomous, no block barriers ----
    const float wfscale = (bmask[b] != 0) ? 0.0f : 0.7f;
    float (*ws)[68] = wsT[w];
    const int mwave = w * 64;

#pragma unroll 1
    for (int s = 0; s < 4; s++) {
        const int mbase = mwave + s * 16;

        // 1. issue this step's HBM loads; consumed after MFMA+transpose
        f32x4 pm[4], pw[4];
#pragma unroll
        for (int j = 0; j < 4; j++) {
            const size_t gi = obase + (size_t)(mbase + rr + 4 * j) * 128 + ebase + c4;
            pm[j] = ntload4(memories + gi);
            pw[j] = ntload4(write_mass + gi);
        }

        // 2. MFMA: acc[h][nt], h=0 update / h=1 logit, nt = 16-e frag
        f32x4 acc[2][4];
#pragma unroll
        for (int h = 0; h < 2; h++)
#pragma unroll
            for (int nt = 0; nt < 4; nt++) acc[h][nt] = (f32x4){0.f, 0.f, 0.f, 0.f};
#pragma unroll
        for (int ks = 0; ks < 4; ks++) {
            const half8 af = *(const half8*)(aqH + (size_t)(mbase + col) * 128
                                             + ks * 32 + q * 8);
#pragma unroll
            for (int h = 0; h < 2; h++)
#pragma unroll
                for (int nt = 0; nt < 4; nt++) {
                    const half8 bf = *(const half8*)&matT[h * 64 + nt * 16 + col]
                                                         [ks * 32 + q * 8];
                    acc[h][nt] = __builtin_amdgcn_mfma_f32_16x16x32_f16(af, bf,
                                                                        acc[h][nt], 0, 0, 0);
                }
        }

        // 3. in-wave transpose: update tile
#pragma unroll
        for (int r = 0; r < 4; r++)
#pragma unroll
            for (int nt = 0; nt < 4; nt++)
                ws[q * 4 + r][nt * 16 + col] = acc[0][nt][r];
        __builtin_amdgcn_wave_barrier();
        f32x4 u[4];
#pragma unroll
        for (int j = 0; j < 4; j++) u[j] = *(const f32x4*)&ws[rr + 4 * j][c4];
        __builtin_amdgcn_wave_barrier();
        // logit tile
#pragma unroll
        for (int r = 0; r < 4; r++)
#pragma unroll
            for (int nt = 0; nt < 4; nt++)
                ws[q * 4 + r][nt * 16 + col] = acc[1][nt][r];
        __builtin_amdgcn_wave_barrier();
        f32x4 g[4];
#pragma unroll
        for (int j = 0; j < 4; j++) g[j] = *(const f32x4*)&ws[rr + 4 * j][c4];
        __builtin_amdgcn_wave_barrier();

        // 4. fused epilogue + IO
#pragma unroll
        for (int j = 0; j < 4; j++) {
            const int m = mbase + rr + 4 * j;
            const float rc = sDen[m];
            const f32x4 si = *(const f32x4*)(sigI + (size_t)m * 128 + ebase + c4);
            const size_t gi = obase + (size_t)m * 128 + ebase + c4;
            f32x4 o1, o2;
#pragma unroll
            for (int jj = 0; jj < 4; jj++) {
                const float upd = u[j][jj] * rc;
                const float wl  = g[j][jj] * rc;
                const float wpb = 1.0f / (1.0f + __expf(-wl));
                const float wf  = wfscale * wpb * si[jj];
                o1[jj] = pm[j][jj] + wf * (upd - pm[j][jj]);
                o2[jj] = pw[j][jj] + wf;
            }
            ntstore4(out + gi, o1);
            ntstore4(out + NMTOT + gi, o2);
        }
    }
}

// ---------------------------------------------------------------------------
extern "C" void kernel_launch(void* const* d_in, const int* in_sizes, int n_in,
                              void* d_out, int out_size, void* d_ws, size_t ws_size,
                              hipStream_t stream) {
    const float* key        = (const float*)d_in[0];
    const float* values     = (const float*)d_in[1];
    const float* memories   = (const float*)d_in[2];
    const float* write_mass = (const float*)d_in[3];
    const unsigned char* bm = (const unsigned char*)d_in[4];
    const float* W_key      = (const float*)d_in[5];
    const float* b_key      = (const float*)d_in[6];
    const float* W_val      = (const float*)d_in[7];
    const float* b_val      = (const float*)d_in[8];
    const float* addresses  = (const float*)d_in[9];
    const float* ilog       = (const float*)d_in[10];
    float* out = (float*)d_out;

    char* ws = (char*)d_ws;
    _Float16* key16 = (_Float16*)ws;  ws += (size_t)512 * 2048 * 2;
    _Float16* val16 = (_Float16*)ws;  ws += (size_t)512 * 2048 * 2;
    _Float16* WkT   = (_Float16*)ws;  ws += (size_t)1024 * 2048 * 2;
    _Float16* WvT   = (_Float16*)ws;  ws += (size_t)2048 * 2048 * 2;
    float*    akF   = (float*)ws;     ws += (size_t)512 * 1024 * 4;
    _Float16* vH    = (_Float16*)ws;  ws += (size_t)512 * 2048 * 2;
    float*    aqF   = (float*)ws;     ws += (size_t)512 * 128 * 4;
    _Float16* aqH   = (_Float16*)ws;  ws += (size_t)512 * 128 * 2;
    float*    sigI  = (float*)ws;     ws += (size_t)512 * 128 * 4;

    prep_all<<<2304, 256, 0, stream>>>(key, values, addresses, ilog,
                                       key16, val16, aqF, aqH, sigI);
    transp_cvt<<<dim3(64, 32), 256, 0, stream>>>(W_key, WkT, 1024);
    transp_cvt<<<dim3(64, 64), 256, 0, stream>>>(W_val, WvT, 2048);
    gemm_kv<<<dim3(8, 48), 256, 0, stream>>>(key16, val16, WkT, WvT, b_key, b_val, akF, vH);
    fused_mem<<<dim3(512, 2), 512, 0, stream>>>(akF, vH, aqH, aqF, sigI, memories, write_mass, bm, out);
}